// Round 1
// baseline (97.018 us; speedup 1.0000x reference)
//
#include <hip/hip_runtime.h>
#include <math.h>

#define NQ 8
#define DIM 256

// Apply a generic complex 2x2 gate on amplitude-index bit b (qubit q = 7-b).
// State: 4 complex amps per lane, index i = (lane<<2)|r.
__device__ __forceinline__ void apply_gate_bit(
    float sr[4], float si[4], int lane, const int b,
    float m00r, float m00i, float m01r, float m01i,
    float m10r, float m10i, float m11r, float m11i)
{
    if (b >= 2) {
        const int lmask = 1 << (b - 2);
        const int myv = (lane >> (b - 2)) & 1;
        // coefficient select instead of divergent branch:
        // myv==0: new = m00*own + m01*partner ; myv==1: new = m11*own + m10*partner
        const float c0r = myv ? m11r : m00r;
        const float c0i = myv ? m11i : m00i;
        const float c1r = myv ? m10r : m01r;
        const float c1i = myv ? m10i : m01i;
#pragma unroll
        for (int r = 0; r < 4; ++r) {
            const float pr = __shfl_xor(sr[r], lmask, 64);
            const float pi = __shfl_xor(si[r], lmask, 64);
            const float ar = c0r * sr[r] - c0i * si[r] + c1r * pr - c1i * pi;
            const float ai = c0r * si[r] + c0i * sr[r] + c1r * pi + c1i * pr;
            sr[r] = ar; si[r] = ai;
        }
    } else {
        const int rmask = 1 << b;
#pragma unroll
        for (int r0 = 0; r0 < 4; ++r0) {
            if (r0 & rmask) continue;          // compile-time (loop unrolled)
            const int r1 = r0 | rmask;
            const float a0r = sr[r0], a0i = si[r0];
            const float a1r = sr[r1], a1i = si[r1];
            sr[r0] = m00r * a0r - m00i * a0i + m01r * a1r - m01i * a1i;
            si[r0] = m00r * a0i + m00i * a0r + m01r * a1i + m01i * a1r;
            sr[r1] = m10r * a0r - m10i * a0i + m11r * a1r - m11i * a1i;
            si[r1] = m10r * a0i + m10i * a0r + m11r * a1i + m11i * a1r;
        }
    }
}

// CNOT: new[i] = (bit_bc(i)==1) ? old[i ^ (1<<bt)] : old[i]
__device__ __forceinline__ void apply_cnot(
    float sr[4], float si[4], int lane, const int bc, const int bt)
{
    if (bt >= 2) {
        const int lmask = 1 << (bt - 2);
#pragma unroll
        for (int r = 0; r < 4; ++r) {
            const float pr = __shfl_xor(sr[r], lmask, 64);
            const float pi = __shfl_xor(si[r], lmask, 64);
            const int idx = (lane << 2) | r;
            const bool ctrl = (idx >> bc) & 1;
            sr[r] = ctrl ? pr : sr[r];
            si[r] = ctrl ? pi : si[r];
        }
    } else {
        const int rmask = 1 << bt;
        float nr[4], ni[4];
#pragma unroll
        for (int r = 0; r < 4; ++r) {
            const int idx = (lane << 2) | r;
            const bool ctrl = (idx >> bc) & 1;
            const int rp = r ^ rmask;
            nr[r] = ctrl ? sr[rp] : sr[r];
            ni[r] = ctrl ? si[rp] : si[r];
        }
#pragma unroll
        for (int r = 0; r < 4; ++r) { sr[r] = nr[r]; si[r] = ni[r]; }
    }
}

__global__ __launch_bounds__(256) void vqe_kernel(
    const float* __restrict__ x,       // (B, 8)
    const float* __restrict__ weights, // (2, 8, 3)
    const float* __restrict__ fc_w,    // (1, 8)
    const float* __restrict__ fc_b,    // (1,)
    float* __restrict__ out,           // (B, 1)
    int B)
{
    const int wave = (int)((blockIdx.x * blockDim.x + threadIdx.x) >> 6);
    const int lane = (int)(threadIdx.x & 63);
    if (wave >= B) return;

    // |00000000>
    float sr[4] = {0.f, 0.f, 0.f, 0.f};
    float si[4] = {0.f, 0.f, 0.f, 0.f};
    if (lane == 0) sr[0] = 1.0f;

    // ---- AngleEmbedding: RX(x[q]) on wire q ----
#pragma unroll
    for (int q = 0; q < NQ; ++q) {
        const float theta = x[wave * NQ + q];
        float s, c;
        __sincosf(theta * 0.5f, &s, &c);
        // RX = [[c, -i s], [-i s, c]]
        apply_gate_bit(sr, si, lane, 7 - q,
                       c, 0.f,   0.f, -s,
                       0.f, -s,  c, 0.f);
    }

    // ---- StronglyEntanglingLayers (2 layers) ----
#pragma unroll
    for (int l = 0; l < 2; ++l) {
#pragma unroll
        for (int q = 0; q < NQ; ++q) {
            const float phi = weights[(l * NQ + q) * 3 + 0];
            const float th  = weights[(l * NQ + q) * 3 + 1];
            const float om  = weights[(l * NQ + q) * 3 + 2];
            float st, ct; __sincosf(th * 0.5f, &st, &ct);
            float sa, ca; __sincosf(0.5f * (phi + om), &sa, &ca);
            float sb, cb; __sincosf(0.5f * (phi - om), &sb, &cb);
            // m00 = ct*(ca,-sa); m01 = -st*(cb, sb); m10 = st*(cb,-sb); m11 = ct*(ca, sa)
            apply_gate_bit(sr, si, lane, 7 - q,
                           ct * ca, -ct * sa,   -st * cb, -st * sb,
                           st * cb, -st * sb,    ct * ca,  ct * sa);
        }
        const int rr = (l % (NQ - 1)) + 1;
#pragma unroll
        for (int q = 0; q < NQ; ++q) {
            const int t = (q + rr) & 7;
            apply_cnot(sr, si, lane, 7 - q, 7 - t);
        }
    }

    // ---- Readout: sigmoid( sum_i p_i * (sum_q sign_q(i)*fc_w[q]) + fc_b ) ----
    float fw[NQ];
#pragma unroll
    for (int q = 0; q < NQ; ++q) fw[q] = fc_w[q];

    float partial = 0.f;
#pragma unroll
    for (int r = 0; r < 4; ++r) {
        const int idx = (lane << 2) | r;
        float w = 0.f;
#pragma unroll
        for (int q = 0; q < NQ; ++q)
            w += ((idx >> (7 - q)) & 1) ? -fw[q] : fw[q];
        partial += (sr[r] * sr[r] + si[r] * si[r]) * w;
    }
#pragma unroll
    for (int off = 1; off < 64; off <<= 1)
        partial += __shfl_xor(partial, off, 64);

    if (lane == 0) {
        const float zf = partial + fc_b[0];
        out[wave] = 1.0f / (1.0f + __expf(-zf));
    }
}

extern "C" void kernel_launch(void* const* d_in, const int* in_sizes, int n_in,
                              void* d_out, int out_size, void* d_ws, size_t ws_size,
                              hipStream_t stream) {
    const float* x       = (const float*)d_in[0];
    const float* weights = (const float*)d_in[1];
    const float* fc_w    = (const float*)d_in[2];
    const float* fc_b    = (const float*)d_in[3];
    float* out = (float*)d_out;

    const int B = in_sizes[0] / NQ;       // 32768
    const int waves_per_block = 4;        // 256 threads
    const int blocks = (B + waves_per_block - 1) / waves_per_block;
    vqe_kernel<<<blocks, 256, 0, stream>>>(x, weights, fc_w, fc_b, out, B);
}

// Round 2
// 38.622 us; speedup vs baseline: 2.5120x; 2.5120x over previous
//
#include <hip/hip_runtime.h>
#include <math.h>

#define NQ 8
#define DIM 256

// ---------- compile-time GF(2) circuit algebra ----------
// wire w <-> index bit (7-w). CNOT(c,t): bit_t ^= bit_c.
__host__ __device__ constexpr int cnot_step(int i, int c, int t) {
    return ((i >> (7 - c)) & 1) ? (i ^ (1 << (7 - t))) : i;
}
// CNOT layer with offset r, applied q=0..7 sequentially (as in reference)
__host__ __device__ constexpr int sigma_fwd(int i, int r) {
    for (int q = 0; q < 8; ++q) i = cnot_step(i, q, (q + r) & 7);
    return i;
}
__host__ __device__ constexpr int sigma_inv(int i, int r) {
    for (int q = 7; q >= 0; --q) i = cnot_step(i, q, (q + r) & 7);
    return i;
}
// layer-2 gate on wire q, conjugated by layer-1 CNOTs:
// pairs s <-> s ^ pairmask(q); role(=row of 2x2) = parity(s & rolemask(q))
__host__ __device__ constexpr int pairmask(int q) { return sigma_inv(1 << (7 - q), 1); }
__host__ __device__ constexpr int rolemask(int q) {
    int m = 0;
    for (int j = 0; j < 8; ++j)
        if ((sigma_fwd(1 << j, 1) >> (7 - q)) & 1) m |= 1 << j;
    return m;
}
// full permutation (both CNOT layers) for readout: columns of the linear map
__host__ __device__ constexpr int colmask(int j) { return sigma_fwd(sigma_fwd(1 << j, 1), 2); }

__device__ __forceinline__ void cmul(float& zr, float& zi,
                                     float xr, float xi, float yr, float yi) {
    const float tr = xr * yr - xi * yi;
    const float ti = xr * yi + xi * yr;
    zr = tr; zi = ti;
}

// Rot(phi,theta,omega) entries per reference formula -> g[8] = {00r,00i,01r,01i,10r,10i,11r,11i}
__device__ __forceinline__ void rot_entries(const float* __restrict__ w3, float g[8]) {
    float s, c;   __sincosf(w3[1] * 0.5f, &s, &c);
    float sa, ca; __sincosf(0.5f * (w3[0] + w3[2]), &sa, &ca);
    float sb, cb; __sincosf(0.5f * (w3[0] - w3[2]), &sb, &cb);
    g[0] = c * ca;  g[1] = -c * sa;
    g[2] = -s * cb; g[3] = -s * sb;
    g[4] = s * cb;  g[5] = -s * sb;
    g[6] = c * ca;  g[7] = c * sa;
}

// Generalized single-"qubit" gate (layer-2 wire Q conjugated through layer-1 CNOTs).
template<int Q>
__device__ __forceinline__ void gate2(float sr[4], float si[4], int lane,
    float m00r, float m00i, float m01r, float m01i,
    float m10r, float m10i, float m11r, float m11i)
{
    constexpr int M     = pairmask(Q);
    constexpr int RM    = rolemask(Q);
    constexpr int mlane = M >> 2;
    constexpr int mreg  = M & 3;

    const bool p = (__popc(lane & (RM >> 2)) & 1) != 0;   // lane part of role parity
    // coefficient set X: role == p ; set Y: role == !p (needed iff role has reg bits)
    const float X0r = p ? m11r : m00r, X0i = p ? m11i : m00i;
    const float X1r = p ? m10r : m01r, X1i = p ? m10i : m01i;
    float Y0r = 0.f, Y0i = 0.f, Y1r = 0.f, Y1i = 0.f;
    if constexpr ((RM & 3) != 0) {
        Y0r = p ? m00r : m11r; Y0i = p ? m00i : m11i;
        Y1r = p ? m01r : m10r; Y1i = p ? m01i : m10i;
    }

    float pr[4], pi[4];
#pragma unroll
    for (int r = 0; r < 4; ++r) {
        float vr = sr[r ^ mreg], vi = si[r ^ mreg];
        if constexpr (mlane != 0) {
            vr = __shfl_xor(vr, mlane, 64);
            vi = __shfl_xor(vi, mlane, 64);
        }
        pr[r] = vr; pi[r] = vi;
    }
#pragma unroll
    for (int r = 0; r < 4; ++r) {
        const int rp = __popc(r & (RM & 3)) & 1;           // compile-time after unroll
        float c0r, c0i, c1r, c1i;
        if constexpr ((RM & 3) != 0) {
            c0r = rp ? Y0r : X0r; c0i = rp ? Y0i : X0i;
            c1r = rp ? Y1r : X1r; c1i = rp ? Y1i : X1i;
        } else {
            (void)rp;
            c0r = X0r; c0i = X0i; c1r = X1r; c1i = X1i;
        }
        const float ar = c0r * sr[r] - c0i * si[r] + c1r * pr[r] - c1i * pi[r];
        const float ai = c0r * si[r] + c0i * sr[r] + c1r * pi[r] + c1i * pr[r];
        sr[r] = ar; si[r] = ai;
    }
}

template<int Q, bool USE_WS>
__device__ __forceinline__ void do_gate2(float sr[4], float si[4], int lane,
                                         const float* __restrict__ ws,
                                         const float* __restrict__ weights)
{
    float g[8];
    if constexpr (USE_WS) {
        const float* gp = ws + 64 + Q * 8;   // layer-1 (second) Rot matrices
#pragma unroll
        for (int k = 0; k < 8; ++k) g[k] = gp[k];
    } else {
        rot_entries(weights + (NQ + Q) * 3, g);
    }
    gate2<Q>(sr, si, lane, g[0], g[1], g[2], g[3], g[4], g[5], g[6], g[7]);
}

// ---------- setup: shared Rot matrices + permuted readout weight table ----------
__global__ void vqe_setup(const float* __restrict__ weights,
                          const float* __restrict__ fc_w,
                          float* __restrict__ ws)
{
    const int t = threadIdx.x;            // 0..255
    if (t < 16) {
        const int l = t >> 3, q = t & 7;
        const float* w3 = weights + (l * NQ + q) * 3;
        const float th = w3[1], phi = w3[0], om = w3[2];
        const float c = cosf(th * 0.5f), s = sinf(th * 0.5f);
        const float ca = cosf(0.5f * (phi + om)), sa = sinf(0.5f * (phi + om));
        const float cb = cosf(0.5f * (phi - om)), sb = sinf(0.5f * (phi - om));
        float* g = ws + t * 8;
        g[0] = c * ca;  g[1] = -c * sa;
        g[2] = -s * cb; g[3] = -s * sb;
        g[4] = s * cb;  g[5] = -s * sb;
        g[6] = c * ca;  g[7] = c * sa;
    }
    // weight table: stored amp s -> physical index sigma2(sigma1(s)) -> signed fc_w sum
    int j = t;
    for (int q = 0; q < 8; ++q) j = cnot_step(j, q, (q + 1) & 7);
    for (int q = 0; q < 8; ++q) j = cnot_step(j, q, (q + 2) & 7);
    float w = 0.f;
    for (int q = 0; q < 8; ++q)
        w += ((j >> (7 - q)) & 1) ? -fc_w[q] : fc_w[q];
    ws[128 + t] = w;
}

// ---------- main kernel: one wave per sample, 4 amps per lane ----------
template<bool USE_WS>
__global__ __launch_bounds__(256) void vqe_main(
    const float* __restrict__ x,       // (B,8)
    const float* __restrict__ weights, // (2,8,3) (only used when !USE_WS)
    const float* __restrict__ fc_w,    // (8)     (only used when !USE_WS)
    const float* __restrict__ fc_b,    // (1)
    const float* __restrict__ ws,      // [0..63]=Rot0, [64..127]=Rot1, [128..383]=wtab
    float* __restrict__ out, int B)
{
    const int wave = (int)((blockIdx.x * blockDim.x + threadIdx.x) >> 6);
    const int lane = (int)(threadIdx.x & 63);
    if (wave >= B) return;
    const int wuni = __builtin_amdgcn_readfirstlane(wave);
    const float* xp = x + wuni * NQ;   // wave-uniform -> scalar loads

    // ---- fused (Rot0 * RX)|0> column per qubit: v_q = (a_q, b_q) ----
    float avr[NQ], avi[NQ], bvr[NQ], bvi[NQ];
#pragma unroll
    for (int q = 0; q < NQ; ++q) {
        float g[8];
        if constexpr (USE_WS) {
            const float* gp = ws + q * 8;
#pragma unroll
            for (int k = 0; k < 8; ++k) g[k] = gp[k];
        } else {
            rot_entries(weights + q * 3, g);
        }
        float s, c; __sincosf(xp[q] * 0.5f, &s, &c);
        // column = c*RotCol0 + (-i s)*RotCol1
        avr[q] = c * g[0] + s * g[3];  avi[q] = c * g[1] - s * g[2];
        bvr[q] = c * g[4] + s * g[7];  bvi[q] = c * g[5] - s * g[6];
    }

    // ---- build product state directly: amp(s) = prod_q v_q[bit_{7-q}(s)] ----
    // index s = (lane<<2)|r ; qubit q in 0..5 <-> lane bit (5-q); q=6 <-> r bit1; q=7 <-> r bit0
    float cr_, ci_;
    {
        const int b = (lane >> 5) & 1;
        cr_ = b ? bvr[0] : avr[0];
        ci_ = b ? bvi[0] : avi[0];
    }
#pragma unroll
    for (int q = 1; q < 6; ++q) {
        const int b = (lane >> (5 - q)) & 1;
        const float yr = b ? bvr[q] : avr[q];
        const float yi = b ? bvi[q] : avi[q];
        cmul(cr_, ci_, cr_, ci_, yr, yi);
    }
    float u0r, u0i, u1r, u1i;
    cmul(u0r, u0i, cr_, ci_, avr[6], avi[6]);
    cmul(u1r, u1i, cr_, ci_, bvr[6], bvi[6]);
    float sr[4], si[4];
    cmul(sr[0], si[0], u0r, u0i, avr[7], avi[7]);
    cmul(sr[1], si[1], u0r, u0i, bvr[7], bvi[7]);
    cmul(sr[2], si[2], u1r, u1i, avr[7], avi[7]);
    cmul(sr[3], si[3], u1r, u1i, bvr[7], bvi[7]);

    // ---- layer-2 Rot gates, conjugated through layer-1 CNOTs (CNOTs are free) ----
    do_gate2<0, USE_WS>(sr, si, lane, ws, weights);
    do_gate2<1, USE_WS>(sr, si, lane, ws, weights);
    do_gate2<2, USE_WS>(sr, si, lane, ws, weights);
    do_gate2<3, USE_WS>(sr, si, lane, ws, weights);
    do_gate2<4, USE_WS>(sr, si, lane, ws, weights);
    do_gate2<5, USE_WS>(sr, si, lane, ws, weights);
    do_gate2<6, USE_WS>(sr, si, lane, ws, weights);
    do_gate2<7, USE_WS>(sr, si, lane, ws, weights);

    // ---- readout: sum |amp|^2 * w(sigma(s)), wave-reduce, sigmoid ----
    float wr[4];
    if constexpr (USE_WS) {
        const float4 wv = ((const float4*)(ws + 128))[lane];
        wr[0] = wv.x; wr[1] = wv.y; wr[2] = wv.z; wr[3] = wv.w;
    } else {
        int pl = 0;
#pragma unroll
        for (int j = 0; j < 6; ++j) pl ^= (-((lane >> j) & 1)) & colmask(j + 2);
        float fw[NQ];
#pragma unroll
        for (int q = 0; q < NQ; ++q) fw[q] = fc_w[q];
#pragma unroll
        for (int r = 0; r < 4; ++r) {
            const int phys = pl ^ ((r & 1) ? colmask(0) : 0) ^ ((r >> 1) ? colmask(1) : 0);
            float w = 0.f;
#pragma unroll
            for (int q = 0; q < NQ; ++q)
                w += ((phys >> (7 - q)) & 1) ? -fw[q] : fw[q];
            wr[r] = w;
        }
    }

    float acc = 0.f;
#pragma unroll
    for (int r = 0; r < 4; ++r)
        acc = fmaf(sr[r] * sr[r] + si[r] * si[r], wr[r], acc);
#pragma unroll
    for (int off = 1; off < 64; off <<= 1)
        acc += __shfl_xor(acc, off, 64);

    if (lane == 0) {
        const float z = acc + fc_b[0];
        out[wave] = 1.0f / (1.0f + __expf(-z));
    }
}

extern "C" void kernel_launch(void* const* d_in, const int* in_sizes, int n_in,
                              void* d_out, int out_size, void* d_ws, size_t ws_size,
                              hipStream_t stream) {
    const float* x       = (const float*)d_in[0];
    const float* weights = (const float*)d_in[1];
    const float* fc_w    = (const float*)d_in[2];
    const float* fc_b    = (const float*)d_in[3];
    float* out = (float*)d_out;
    float* ws  = (float*)d_ws;

    const int B = in_sizes[0] / NQ;      // 32768
    const int blocks = (B + 3) / 4;      // 4 waves (samples) per 256-thread block

    const bool use_ws = (ws != nullptr) && (ws_size >= (128 + 256) * sizeof(float));
    if (use_ws) {
        vqe_setup<<<1, 256, 0, stream>>>(weights, fc_w, ws);
        vqe_main<true><<<blocks, 256, 0, stream>>>(x, weights, fc_w, fc_b, ws, out, B);
    } else {
        vqe_main<false><<<blocks, 256, 0, stream>>>(x, weights, fc_w, fc_b, ws, out, B);
    }
}

// Round 3
// 31.047 us; speedup vs baseline: 3.1248x; 1.2440x over previous
//
#include <hip/hip_runtime.h>
#include <hip/hip_fp16.h>
#include <math.h>

#define NQ 8

// ---------- compile-time GF(2) circuit algebra (validated: round-2 absmax=0) ----------
// wire w <-> amp-index bit (7-w). CNOT(c,t): bit_t ^= bit_c.
__host__ __device__ constexpr int cnot_step(int i, int c, int t) {
    return ((i >> (7 - c)) & 1) ? (i ^ (1 << (7 - t))) : i;
}
__host__ __device__ constexpr int sigma_fwd(int i, int r) {
    for (int q = 0; q < 8; ++q) i = cnot_step(i, q, (q + r) & 7);
    return i;
}
__host__ __device__ constexpr int sigma_inv(int i, int r) {
    for (int q = 7; q >= 0; --q) i = cnot_step(i, q, (q + r) & 7);
    return i;
}
// layer-2 gate on wire q conjugated through layer-1 CNOTs:
// pairs s <-> s ^ pairmask(q); role = parity(s & rolemask(q))
__host__ __device__ constexpr int pairmask(int q) { return sigma_inv(1 << (7 - q), 1); }
__host__ __device__ constexpr int rolemask(int q) {
    int m = 0;
    for (int j = 0; j < 8; ++j)
        if ((sigma_fwd(1 << j, 1) >> (7 - q)) & 1) m |= 1 << j;
    return m;
}

__device__ __forceinline__ __half2 bc_h2(uint32_t u) {
    return __builtin_bit_cast(__half2, u);
}
__device__ __forceinline__ uint32_t bc_u32(__half2 h) {
    return __builtin_bit_cast(uint32_t, h);
}
__device__ __forceinline__ __half2 h2swap(__half2 v) {   // {re,im} -> {im,re}
    uint32_t u = bc_u32(v);
    u = (u >> 16) | (u << 16);
    return bc_h2(u);
}
__device__ __forceinline__ void cmul(float& zr, float& zi,
                                     float xr, float xi, float yr, float yi) {
    const float tr = xr * yr - xi * yi;
    const float ti = xr * yi + xi * yr;
    zr = tr; zi = ti;
}

// ---------- setup: layer-0 Rot matrices (f32), layer-1 packed-f16 coeff pairs, wtab ----------
// ws layout (float words):
//   [0..63]    layer-0 Rot g[8] per qubit (f32)
//   [64..95]   layer-1 packed pairs, u32: per gate q: {A,A},{B,-B},{-C,-C},{D,-D} (f16x2)
//   [128..383] wtab: stored amp s -> w(sigma2(sigma1(s))) (f32)
__global__ void vqe_setup(const float* __restrict__ weights,
                          const float* __restrict__ fc_w,
                          float* __restrict__ ws)
{
    const int t = threadIdx.x;            // 0..255
    if (t < 8) {
        const float* w3 = weights + t * 3;
        const float c = cosf(w3[1] * 0.5f), s = sinf(w3[1] * 0.5f);
        const float ca = cosf(0.5f * (w3[0] + w3[2])), sa = sinf(0.5f * (w3[0] + w3[2]));
        const float cb = cosf(0.5f * (w3[0] - w3[2])), sb = sinf(0.5f * (w3[0] - w3[2]));
        float* g = ws + t * 8;
        g[0] = c * ca;  g[1] = -c * sa;
        g[2] = -s * cb; g[3] = -s * sb;
        g[4] = s * cb;  g[5] = -s * sb;
        g[6] = c * ca;  g[7] = c * sa;
    } else if (t < 16) {
        const int q = t - 8;
        const float* w3 = weights + (NQ + q) * 3;
        const float c = cosf(w3[1] * 0.5f), s = sinf(w3[1] * 0.5f);
        const float ca = cosf(0.5f * (w3[0] + w3[2])), sa = sinf(0.5f * (w3[0] + w3[2]));
        const float cb = cosf(0.5f * (w3[0] - w3[2])), sb = sinf(0.5f * (w3[0] - w3[2]));
        // m00=(A,-B) m11=(A,B) m10=(C,-D) m01=(-C,-D)
        const float A = c * ca, B = c * sa, C = s * cb, D = s * sb;
        uint32_t* cw = (uint32_t*)ws + 64;
        cw[q * 4 + 0] = __builtin_bit_cast(uint32_t, __floats2half2_rn(A, A));
        cw[q * 4 + 1] = __builtin_bit_cast(uint32_t, __floats2half2_rn(B, -B));
        cw[q * 4 + 2] = __builtin_bit_cast(uint32_t, __floats2half2_rn(-C, -C));
        cw[q * 4 + 3] = __builtin_bit_cast(uint32_t, __floats2half2_rn(D, -D));
    }
    int j = t;
    for (int q = 0; q < 8; ++q) j = cnot_step(j, q, (q + 1) & 7);
    for (int q = 0; q < 8; ++q) j = cnot_step(j, q, (q + 2) & 7);
    float w = 0.f;
    for (int q = 0; q < 8; ++q)
        w += ((j >> (7 - q)) & 1) ? -fc_w[q] : fc_w[q];
    ws[128 + t] = w;
}

// ---------- generalized layer-2 gate, packed f16, 8 amps/lane ----------
// amp index s = ((lane&31)<<3) | r ; role0: new = m00*s + m01*p ; role1: new = m10*p + m11*s
// (ar,ai) = {A,A}*(sr,si) + sgn*{B,-B}*(si,sr) + sgn*{-C,-C}*(pr,pi) + {D,-D}*(pi,pr)
template<int Q>
__device__ __forceinline__ void gate2h(__half2 st[8], int hl, uint4 cq)
{
    constexpr int M     = pairmask(Q);
    constexpr int RM    = rolemask(Q);
    constexpr int mlane = (M >> 3) & 31;
    constexpr int mreg  = M & 7;
    constexpr int rl    = (RM >> 3) & 31;
    constexpr int rr    = RM & 7;

    const uint32_t pm  = (uint32_t)(__popc(hl & rl) & 1) * 0x80008000u;
    const uint32_t Bp0 = cq.y ^ pm;
    const uint32_t Cp0 = cq.z ^ pm;
    const uint32_t Bp1 = Bp0 ^ 0x80008000u;   // dead-code-eliminated when rr==0
    const uint32_t Cp1 = Cp0 ^ 0x80008000u;

    uint32_t pp[8];
#pragma unroll
    for (int r = 0; r < 8; ++r) {
        uint32_t v = bc_u32(st[r ^ mreg]);
        if constexpr (mlane != 0)
            v = (uint32_t)__shfl_xor((int)v, mlane, 64);   // mask<32: stays in half-wave
        pp[r] = v;
    }
    const __half2 Ah = bc_h2(cq.x);
    const __half2 Dh = bc_h2(cq.w);
#pragma unroll
    for (int r = 0; r < 8; ++r) {
        const bool rp = (__popc(r & rr) & 1) != 0;          // compile-time after unroll
        const __half2 Bh = bc_h2(rp ? Bp1 : Bp0);
        const __half2 Ch = bc_h2(rp ? Cp1 : Cp0);
        const __half2 sv = st[r];
        const __half2 pv = bc_h2(pp[r]);
        __half2 acc = __hmul2(Ah, sv);
        acc = __hfma2(Bh, h2swap(sv), acc);
        acc = __hfma2(Ch, pv, acc);
        acc = __hfma2(Dh, h2swap(pv), acc);
        st[r] = acc;
    }
}

// ---------- main: one wave = 2 samples (half-wave each), 8 amps/lane packed f16 ----------
__global__ __launch_bounds__(256) void vqe_main(
    const float* __restrict__ x,     // (B,8)
    const float* __restrict__ fc_b,  // (1,)
    const float* __restrict__ ws,
    float* __restrict__ out, int B)
{
    const int wid  = (int)((blockIdx.x * blockDim.x + threadIdx.x) >> 6);
    const int lane = (int)(threadIdx.x & 63);
    const int half = lane >> 5;
    const int hl   = lane & 31;
    const int samp = wid * 2 + half;
    if (samp >= B) return;

    const float4 x0 = ((const float4*)(x + samp * NQ))[0];
    const float4 x1 = ((const float4*)(x + samp * NQ))[1];
    const float xq[8] = {x0.x, x0.y, x0.z, x0.w, x1.x, x1.y, x1.z, x1.w};

    // fused (Rot0 * RX)|0> column per qubit: v_q = (a_q, b_q)
    float avr[8], avi[8], bvr[8], bvi[8];
#pragma unroll
    for (int q = 0; q < 8; ++q) {
        const float* g = ws + q * 8;     // wave-uniform -> scalar loads
        float sn, cs; __sincosf(xq[q] * 0.5f, &sn, &cs);
        avr[q] = cs * g[0] + sn * g[3];
        avi[q] = cs * g[1] - sn * g[2];
        bvr[q] = cs * g[4] + sn * g[7];
        bvi[q] = cs * g[5] - sn * g[6];
    }

    // product state: qubits 0..4 <-> hl bits 4..0 ; qubits 5,6,7 <-> r bits 2,1,0
    float cr, ci;
    { const int b = (hl >> 4) & 1; cr = b ? bvr[0] : avr[0]; ci = b ? bvi[0] : avi[0]; }
#pragma unroll
    for (int q = 1; q < 5; ++q) {
        const int b = (hl >> (4 - q)) & 1;
        const float yr = b ? bvr[q] : avr[q];
        const float yi = b ? bvi[q] : avi[q];
        cmul(cr, ci, cr, ci, yr, yi);
    }
    float ur[2], ui[2];
    cmul(ur[0], ui[0], cr, ci, avr[5], avi[5]);
    cmul(ur[1], ui[1], cr, ci, bvr[5], bvi[5]);
    float t4r[4], t4i[4];
    cmul(t4r[0], t4i[0], ur[0], ui[0], avr[6], avi[6]);
    cmul(t4r[1], t4i[1], ur[0], ui[0], bvr[6], bvi[6]);
    cmul(t4r[2], t4i[2], ur[1], ui[1], avr[6], avi[6]);
    cmul(t4r[3], t4i[3], ur[1], ui[1], bvr[6], bvi[6]);

    __half2 st[8];
#pragma unroll
    for (int r = 0; r < 8; ++r) {
        const int i2 = r >> 1;                       // (b5<<1)|b6
        const float vr = (r & 1) ? bvr[7] : avr[7];
        const float vi = (r & 1) ? bvi[7] : avi[7];
        const float ar = t4r[i2] * vr - t4i[i2] * vi;
        const float ai = t4r[i2] * vi + t4i[i2] * vr;
        st[r] = __floats2half2_rn(ar, ai);
    }

    // layer-2 Rot gates (CNOT layers folded away)
    const uint4* cw = (const uint4*)((const uint32_t*)ws + 64);
    gate2h<0>(st, hl, cw[0]);
    gate2h<1>(st, hl, cw[1]);
    gate2h<2>(st, hl, cw[2]);
    gate2h<3>(st, hl, cw[3]);
    gate2h<4>(st, hl, cw[4]);
    gate2h<5>(st, hl, cw[5]);
    gate2h<6>(st, hl, cw[6]);
    gate2h<7>(st, hl, cw[7]);

    // readout: sum |amp|^2 * wtab[s], half-wave reduce, sigmoid
    const float* wt = ws + 128 + (hl << 3);
    const float4 w0 = ((const float4*)wt)[0];
    const float4 w1 = ((const float4*)wt)[1];
    const float wr[8] = {w0.x, w0.y, w0.z, w0.w, w1.x, w1.y, w1.z, w1.w};

    float acc = 0.f;
#pragma unroll
    for (int r = 0; r < 8; ++r) {
        const float ar = __low2float(st[r]);
        const float ai = __high2float(st[r]);
        acc = fmaf(ar * ar + ai * ai, wr[r], acc);
    }
#pragma unroll
    for (int off = 1; off < 32; off <<= 1)
        acc += __shfl_xor(acc, off, 64);

    if (hl == 0) {
        const float z = acc + fc_b[0];
        out[samp] = 1.0f / (1.0f + __expf(-z));
    }
}

extern "C" void kernel_launch(void* const* d_in, const int* in_sizes, int n_in,
                              void* d_out, int out_size, void* d_ws, size_t ws_size,
                              hipStream_t stream) {
    const float* x       = (const float*)d_in[0];
    const float* weights = (const float*)d_in[1];
    const float* fc_w    = (const float*)d_in[2];
    const float* fc_b    = (const float*)d_in[3];
    float* out = (float*)d_out;
    float* ws  = (float*)d_ws;

    const int B = in_sizes[0] / NQ;        // 32768
    const int waves  = (B + 1) / 2;        // 2 samples per wave
    const int blocks = (waves + 3) / 4;    // 4 waves per 256-thread block

    vqe_setup<<<1, 256, 0, stream>>>(weights, fc_w, ws);
    vqe_main<<<blocks, 256, 0, stream>>>(x, fc_b, ws, out, B);
}

// Round 5
// 26.324 us; speedup vs baseline: 3.6856x; 1.1794x over previous
//
#include <hip/hip_runtime.h>
#include <hip/hip_fp16.h>
#include <math.h>

#define NQ 8

// ---------- compile-time GF(2) circuit algebra (validated: round-2 absmax=0) ----------
// wire w <-> amp-index bit (7-w). CNOT(c,t): bit_t ^= bit_c.
__host__ __device__ constexpr int cnot_step(int i, int c, int t) {
    return ((i >> (7 - c)) & 1) ? (i ^ (1 << (7 - t))) : i;
}
__host__ __device__ constexpr int sigma_fwd(int i, int r) {
    for (int q = 0; q < 8; ++q) i = cnot_step(i, q, (q + r) & 7);
    return i;
}
__host__ __device__ constexpr int sigma_inv(int i, int r) {
    for (int q = 7; q >= 0; --q) i = cnot_step(i, q, (q + r) & 7);
    return i;
}
// layer-2 gate on wire q conjugated through layer-1 CNOTs
__host__ __device__ constexpr int pairmask(int q) { return sigma_inv(1 << (7 - q), 1); }
__host__ __device__ constexpr int rolemask(int q) {
    int m = 0;
    for (int j = 0; j < 8; ++j)
        if ((sigma_fwd(1 << j, 1) >> (7 - q)) & 1) m |= 1 << j;
    return m;
}
// column of the full (both CNOT layers) linear permutation
__host__ __device__ constexpr int colmask2(int b) {
    return sigma_fwd(sigma_fwd(1 << b, 1), 2);
}

__device__ __forceinline__ __half2 bc_h2(uint32_t u) { return __builtin_bit_cast(__half2, u); }
__device__ __forceinline__ uint32_t bc_u32(__half2 h) { return __builtin_bit_cast(uint32_t, h); }
// {re,im} -> {im,re}: 16-bit rotate of the 32-bit pair (one v_alignbit_b32)
__device__ __forceinline__ __half2 h2swap(__half2 v) {
    uint32_t u = bc_u32(v);
    u = (u >> 16) | (u << 16);
    return bc_h2(u);
}

// lane' = lane ^ XM within each 32-lane half (BitMode ds_swizzle, no addr VGPR)
template<int XM>
__device__ __forceinline__ uint32_t swzu(uint32_t v) {
    return (uint32_t)__builtin_amdgcn_ds_swizzle((int)v, (XM << 10) | 0x1F);
}
template<int XM>
__device__ __forceinline__ float swzf(float v) {
    return __builtin_bit_cast(float, (uint32_t)__builtin_amdgcn_ds_swizzle(
        (int)__builtin_bit_cast(uint32_t, v), (XM << 10) | 0x1F));
}

__device__ __forceinline__ void cmul(float& zr, float& zi,
                                     float xr, float xi, float yr, float yi) {
    const float tr = xr * yr - xi * yi;
    const float ti = xr * yi + xi * yr;
    zr = tr; zi = ti;
}

// ---------- generalized layer-2 gate, packed f16, 8 amps/lane ----------
// amp s = ((lane&31)<<3) | r ; pairs s <-> s^pairmask ; role = parity(s & rolemask)
// role only sign-flips the B/C coefficient pairs (one XOR of 0x80008000)
template<int Q>
__device__ __forceinline__ void gate2h(__half2 st[8], int hl, uint4 cq)
{
    constexpr int M     = pairmask(Q);
    constexpr int RM    = rolemask(Q);
    constexpr int mlane = (M >> 3) & 31;
    constexpr int mreg  = M & 7;
    constexpr int rl    = (RM >> 3) & 31;
    constexpr int rr    = RM & 7;

    const uint32_t pm  = (uint32_t)(__popc(hl & rl) & 1) * 0x80008000u;
    const uint32_t Bp0 = cq.y ^ pm;
    const uint32_t Cp0 = cq.z ^ pm;
    const uint32_t Bp1 = Bp0 ^ 0x80008000u;   // DCE'd when rr==0
    const uint32_t Cp1 = Cp0 ^ 0x80008000u;

    uint32_t pp[8];
#pragma unroll
    for (int r = 0; r < 8; ++r) {
        uint32_t v = bc_u32(st[r ^ mreg]);
        if constexpr (mlane != 0) v = swzu<mlane>(v);
        pp[r] = v;
    }
    const __half2 Ah = bc_h2(cq.x);
    const __half2 Dh = bc_h2(cq.w);
#pragma unroll
    for (int r = 0; r < 8; ++r) {
        const bool rp = (__popc(r & rr) & 1) != 0;   // compile-time after unroll
        const __half2 Bh = bc_h2(rp ? Bp1 : Bp0);
        const __half2 Ch = bc_h2(rp ? Cp1 : Cp0);
        const __half2 sv = st[r];
        const __half2 pv = bc_h2(pp[r]);
        __half2 acc = __hmul2(Ah, sv);
        acc = __hfma2(Bh, h2swap(sv), acc);
        acc = __hfma2(Ch, pv, acc);
        acc = __hfma2(Dh, h2swap(pv), acc);
        st[r] = acc;
    }
}

// full column of (Rot_l0[q] * RX(x_q)) |0>
__device__ __forceinline__ void colq(const float* __restrict__ g,
                                     float xh,
                                     float& ar, float& ai, float& br, float& bi) {
    float sn, cs; __sincosf(xh, &sn, &cs);
    ar = cs * g[0] + sn * g[3];
    ai = cs * g[1] - sn * g[2];
    br = cs * g[4] + sn * g[7];
    bi = cs * g[5] - sn * g[6];
}

// ---------- single fused kernel: per-block LDS setup + 2 samples/wave ----------
__global__ __launch_bounds__(256) void vqe_fused(
    const float* __restrict__ x,       // (B,8)
    const float* __restrict__ weights, // (2,8,3)
    const float* __restrict__ fc_w,    // (8)
    const float* __restrict__ fc_b,    // (1)
    float* __restrict__ out, int B)
{
    __shared__ __align__(16) float    g0[64];    // layer-0 Rot entries (f32)
    __shared__ __align__(16) uint32_t cw[32];    // layer-1 packed f16 coeff pairs
    __shared__ __align__(16) float    wtab[256]; // stored amp s -> w(sigma(s))

    const int t = threadIdx.x;

    // --- per-block setup (parallel, ~30 ALU/thread) ---
    if (t < 16) {
        const int l = t >> 3, q = t & 7;
        const float* w3 = weights + (l * NQ + q) * 3;
        float s, c;   __sincosf(w3[1] * 0.5f, &s, &c);
        float sa, ca; __sincosf(0.5f * (w3[0] + w3[2]), &sa, &ca);
        float sb, cb; __sincosf(0.5f * (w3[0] - w3[2]), &sb, &cb);
        if (l == 0) {
            float* g = g0 + q * 8;
            g[0] = c * ca;  g[1] = -c * sa;
            g[2] = -s * cb; g[3] = -s * sb;
            g[4] = s * cb;  g[5] = -s * sb;
            g[6] = c * ca;  g[7] = c * sa;
        } else {
            // m00=(A,-B) m11=(A,B) m10=(C,-D) m01=(-C,-D)
            const float A = c * ca, Bc = c * sa, C = s * cb, D = s * sb;
            cw[q * 4 + 0] = bc_u32(__floats2half2_rn(A, A));
            cw[q * 4 + 1] = bc_u32(__floats2half2_rn(Bc, -Bc));
            cw[q * 4 + 2] = bc_u32(__floats2half2_rn(-C, -C));
            cw[q * 4 + 3] = bc_u32(__floats2half2_rn(D, -D));
        }
    }
    {
        // phys index = linear map of s: j = XOR of colmask2 over set bits
        int j = 0;
#pragma unroll
        for (int b = 0; b < 8; ++b)
            if ((t >> b) & 1) j ^= colmask2(b);
        float w = 0.f;
#pragma unroll
        for (int q = 0; q < 8; ++q)
            w += ((j >> (7 - q)) & 1) ? -fc_w[q] : fc_w[q];
        wtab[t] = w;
    }
    __syncthreads();

    // --- main path: one half-wave per sample, 8 amps/lane ---
    const int lane = t & 63;
    const int hl   = lane & 31;
    const int samp = (int)((blockIdx.x * blockDim.x + t) >> 6) * 2 + (lane >> 5);
    if (samp >= B) return;

    const float4 x0 = ((const float4*)(x + samp * NQ))[0];
    const float4 x1 = ((const float4*)(x + samp * NQ))[1];
    const float xq[8] = {x0.x, x0.y, x0.z, x0.w, x1.x, x1.y, x1.z, x1.w};

    // qubits 0..4 <-> hl bits 4..0: selected column directly via pointer offset
    float cr, ci;
    {
        const float* g = g0 + ((hl >> 4) & 1) * 4;
        float sn, cs; __sincosf(xq[0] * 0.5f, &sn, &cs);
        cr = cs * g[0] + sn * g[3];
        ci = cs * g[1] - sn * g[2];
    }
#pragma unroll
    for (int q = 1; q < 5; ++q) {
        const float* g = g0 + q * 8 + ((hl >> (4 - q)) & 1) * 4;
        float sn, cs; __sincosf(xq[q] * 0.5f, &sn, &cs);
        const float yr = cs * g[0] + sn * g[3];
        const float yi = cs * g[1] - sn * g[2];
        cmul(cr, ci, cr, ci, yr, yi);
    }

    // qubits 5,6,7 <-> r bits 2,1,0: full columns, tail tensor product
    float a5r, a5i, b5r, b5i, a6r, a6i, b6r, b6i, a7r, a7i, b7r, b7i;
    colq(g0 + 5 * 8, xq[5] * 0.5f, a5r, a5i, b5r, b5i);
    colq(g0 + 6 * 8, xq[6] * 0.5f, a6r, a6i, b6r, b6i);
    colq(g0 + 7 * 8, xq[7] * 0.5f, a7r, a7i, b7r, b7i);

    float ur[2], ui[2];
    cmul(ur[0], ui[0], cr, ci, a5r, a5i);
    cmul(ur[1], ui[1], cr, ci, b5r, b5i);
    float t4r[4], t4i[4];
    cmul(t4r[0], t4i[0], ur[0], ui[0], a6r, a6i);
    cmul(t4r[1], t4i[1], ur[0], ui[0], b6r, b6i);
    cmul(t4r[2], t4i[2], ur[1], ui[1], a6r, a6i);
    cmul(t4r[3], t4i[3], ur[1], ui[1], b6r, b6i);

    __half2 st[8];
#pragma unroll
    for (int r = 0; r < 8; ++r) {
        const int i2 = r >> 1;
        const float vr = (r & 1) ? b7r : a7r;
        const float vi = (r & 1) ? b7i : a7i;
        st[r] = __floats2half2_rn(t4r[i2] * vr - t4i[i2] * vi,
                                  t4r[i2] * vi + t4i[i2] * vr);
    }

    // layer-2 Rot gates (CNOT layers folded away)
    const uint4* cwv = (const uint4*)cw;
    gate2h<0>(st, hl, cwv[0]);
    gate2h<1>(st, hl, cwv[1]);
    gate2h<2>(st, hl, cwv[2]);
    gate2h<3>(st, hl, cwv[3]);
    gate2h<4>(st, hl, cwv[4]);
    gate2h<5>(st, hl, cwv[5]);
    gate2h<6>(st, hl, cwv[6]);
    gate2h<7>(st, hl, cwv[7]);

    // readout: sum |amp|^2 * wtab[s], half-wave reduce, sigmoid
    const float4 w0 = ((const float4*)(wtab + (hl << 3)))[0];
    const float4 w1 = ((const float4*)(wtab + (hl << 3)))[1];
    const float wr[8] = {w0.x, w0.y, w0.z, w0.w, w1.x, w1.y, w1.z, w1.w};

    float acc = 0.f;
#pragma unroll
    for (int r = 0; r < 8; ++r) {
        const float ar = __low2float(st[r]);
        const float ai = __high2float(st[r]);
        acc = fmaf(ar * ar + ai * ai, wr[r], acc);
    }
    acc += swzf<1>(acc);
    acc += swzf<2>(acc);
    acc += swzf<4>(acc);
    acc += swzf<8>(acc);
    acc += swzf<16>(acc);

    if (hl == 0) {
        const float z = acc + fc_b[0];
        out[samp] = 1.0f / (1.0f + __expf(-z));
    }
}

extern "C" void kernel_launch(void* const* d_in, const int* in_sizes, int n_in,
                              void* d_out, int out_size, void* d_ws, size_t ws_size,
                              hipStream_t stream) {
    const float* x       = (const float*)d_in[0];
    const float* weights = (const float*)d_in[1];
    const float* fc_w    = (const float*)d_in[2];
    const float* fc_b    = (const float*)d_in[3];
    float* out = (float*)d_out;

    const int B = in_sizes[0] / NQ;        // 32768
    const int waves  = (B + 1) / 2;        // 2 samples per wave
    const int blocks = (waves + 3) / 4;    // 4 waves per 256-thread block

    vqe_fused<<<blocks, 256, 0, stream>>>(x, weights, fc_w, fc_b, out, B);
}

// Round 6
// 20.981 us; speedup vs baseline: 4.6242x; 1.2547x over previous
//
#include <hip/hip_runtime.h>
#include <hip/hip_fp16.h>
#include <math.h>

#define NQ 8

// ---------- compile-time GF(2) circuit algebra (validated: round-2 absmax=0) ----------
// wire w <-> amp-index bit (7-w). CNOT(c,t): bit_t ^= bit_c.
__host__ __device__ constexpr int cnot_step(int i, int c, int t) {
    return ((i >> (7 - c)) & 1) ? (i ^ (1 << (7 - t))) : i;
}
__host__ __device__ constexpr int sigma_fwd(int i, int r) {
    for (int q = 0; q < 8; ++q) i = cnot_step(i, q, (q + r) & 7);
    return i;
}
__host__ __device__ constexpr int sigma_inv(int i, int r) {
    for (int q = 7; q >= 0; --q) i = cnot_step(i, q, (q + r) & 7);
    return i;
}
__host__ __device__ constexpr int pairmask(int q) { return sigma_inv(1 << (7 - q), 1); }
__host__ __device__ constexpr int rolemask(int q) {
    int m = 0;
    for (int j = 0; j < 8; ++j)
        if ((sigma_fwd(1 << j, 1) >> (7 - q)) & 1) m |= 1 << j;
    return m;
}
__host__ __device__ constexpr int colmask2(int b) {
    return sigma_fwd(sigma_fwd(1 << b, 1), 2);
}

// ---------- amp-index bit assignment (4 samples/wave, 16 amps/lane, SoA f16x2) ----------
// amp s bits: b7=slot, b6=k2, b5=l3, b4=l2, b3=l1, b2=l0, b1=k1, b0=k0
// (lane bits {b5..b2} chosen so gates G0,G6,G7 are register-local)
__host__ __device__ constexpr int amp_index(int slot, int k, int hl) {
    return (slot << 7) | (((k >> 2) & 1) << 6) | (((hl >> 3) & 1) << 5)
         | (((hl >> 2) & 1) << 4) | (((hl >> 1) & 1) << 3) | ((hl & 1) << 2)
         | (((k >> 1) & 1) << 1) | (k & 1);
}
__host__ __device__ constexpr int mask_slot(int M) { return (M >> 7) & 1; }
__host__ __device__ constexpr int mask_k(int M) {
    return (((M >> 6) & 1) << 2) | (((M >> 1) & 1) << 1) | (M & 1);
}
__host__ __device__ constexpr int mask_l(int M) { return (M >> 2) & 15; }

__device__ __forceinline__ __half2 bc_h2(uint32_t u) { return __builtin_bit_cast(__half2, u); }
__device__ __forceinline__ uint32_t bc_u32(__half2 h) { return __builtin_bit_cast(uint32_t, h); }
__device__ __forceinline__ uint32_t rot16(uint32_t u) { return (u >> 16) | (u << 16); }

// lane' = lane ^ XM (XM<16 stays within each 16-lane sample group)
template<int XM>
__device__ __forceinline__ uint32_t swzu(uint32_t v) {
    return (uint32_t)__builtin_amdgcn_ds_swizzle((int)v, (XM << 10) | 0x1F);
}
template<int XM>
__device__ __forceinline__ float swzf(float v) {
    return __builtin_bit_cast(float, (uint32_t)__builtin_amdgcn_ds_swizzle(
        (int)__builtin_bit_cast(uint32_t, v), (XM << 10) | 0x1F));
}

__device__ __forceinline__ void cmul(float& zr, float& zi,
                                     float xr, float xi, float yr, float yi) {
    const float tr = xr * yr - xi * yi;
    const float ti = xr * yi + xi * yr;
    zr = tr; zi = ti;
}

// full column pair of (Rot_l0[q] * RX(x_q)) |0>
__device__ __forceinline__ void colq(const float* __restrict__ g, float xh,
                                     float& ar, float& ai, float& br, float& bi) {
    float sn, cs; __sincosf(xh, &sn, &cs);
    ar = cs * g[0] + sn * g[3];
    ai = cs * g[1] - sn * g[2];
    br = cs * g[4] + sn * g[7];
    bi = cs * g[5] - sn * g[6];
}

// ---------- generalized layer-2 gate, SoA packed f16, 16 amps/lane ----------
// nre = A*re + rB*im - rC*pre + D*pim ; nim = A*im - rB*re - rC*pim - D*pre
// r(role sign) = lane-par (runtime XOR) * reg-par (variant select) * slot-par (baked)
template<int Q>
__device__ __forceinline__ void gateQ(__half2 re[8], __half2 im[8], int hl,
                                      const uint32_t* __restrict__ cw)
{
    constexpr int M  = pairmask(Q);
    constexpr int RM = rolemask(Q);
    constexpr int mk = mask_k(M);
    constexpr int ml = mask_l(M);
    constexpr int ms = mask_slot(M);
    constexpr int rk = mask_k(RM);
    constexpr int rl = mask_l(RM);

    const uint4    c4  = *(const uint4*)(cw + Q * 8); // {WA, WB0, WC0(-C), WD}
    const uint32_t WDn = cw[Q * 8 + 4];               // {-D,-D}

    const uint32_t pm = (uint32_t)(__popc(hl & rl) & 1) * 0x80008000u;
    const uint32_t Bp = c4.y ^ pm, Bn = Bp ^ 0x80008000u;
    const uint32_t Cp = c4.z ^ pm, Cn = Cp ^ 0x80008000u;
    const __half2  Aw = bc_h2(c4.x);
    const __half2  Dw = bc_h2(c4.w);
    const __half2  Dn = bc_h2(WDn);

    uint32_t pre[8], pim[8];
#pragma unroll
    for (int k = 0; k < 8; ++k) {
        uint32_t vr = bc_u32(re[k ^ mk]);
        uint32_t vi = bc_u32(im[k ^ mk]);
        if constexpr (ms) { vr = rot16(vr); vi = rot16(vi); }
        if constexpr (ml) { vr = swzu<ml>(vr); vi = swzu<ml>(vi); }
        pre[k] = vr; pim[k] = vi;
    }
#pragma unroll
    for (int k = 0; k < 8; ++k) {
        const bool par = (__popc(k & rk) & 1) != 0;   // compile-time after unroll
        const __half2 B1 = bc_h2(par ? Bn : Bp);      // +rB (for nre)
        const __half2 B2 = bc_h2(par ? Bp : Bn);      // -rB (for nim)
        const __half2 Cc = bc_h2(par ? Cn : Cp);      // -rC (both)
        __half2 nr = __hmul2(Aw, re[k]);
        nr = __hfma2(B1, im[k], nr);
        nr = __hfma2(Cc, bc_h2(pre[k]), nr);
        nr = __hfma2(Dw, bc_h2(pim[k]), nr);
        __half2 ni = __hmul2(Aw, im[k]);
        ni = __hfma2(B2, re[k], ni);
        ni = __hfma2(Cc, bc_h2(pim[k]), ni);
        ni = __hfma2(Dn, bc_h2(pre[k]), ni);
        re[k] = nr; im[k] = ni;
    }
}

// ---------- single fused kernel ----------
__global__ __launch_bounds__(256) void vqe_fused(
    const float* __restrict__ x,       // (B,8)
    const float* __restrict__ weights, // (2,8,3)
    const float* __restrict__ fc_w,    // (8)
    const float* __restrict__ fc_b,    // (1)
    float* __restrict__ out, int B)
{
    __shared__ __align__(16) float    g0[64];        // layer-0 Rot entries (f32)
    __shared__ __align__(16) uint32_t cw[64];        // layer-1 coeff words, 8/gate
    __shared__ __align__(16) float    wtab[16 * 20]; // [hl][k*2+slot], stride 20 (pad)

    const int t = threadIdx.x;

    // --- per-block setup ---
    if (t < 8) {
        const float* w3 = weights + t * 3;
        float s, c;   __sincosf(w3[1] * 0.5f, &s, &c);
        float sa, ca; __sincosf(0.5f * (w3[0] + w3[2]), &sa, &ca);
        float sb, cb; __sincosf(0.5f * (w3[0] - w3[2]), &sb, &cb);
        float* g = g0 + t * 8;
        g[0] = c * ca;  g[1] = -c * sa;
        g[2] = -s * cb; g[3] = -s * sb;
        g[4] = s * cb;  g[5] = -s * sb;
        g[6] = c * ca;  g[7] = c * sa;
    } else if (t < 16) {
        const int q = t - 8;
        const float* w3 = weights + (NQ + q) * 3;
        float s, c;   __sincosf(w3[1] * 0.5f, &s, &c);
        float sa, ca; __sincosf(0.5f * (w3[0] + w3[2]), &sa, &ca);
        float sb, cb; __sincosf(0.5f * (w3[0] - w3[2]), &sb, &cb);
        const float A = c * ca, Bc = c * sa, C = s * cb, D = s * sb;
        const float s1 = (rolemask(q) & 0x80) ? -1.f : 1.f;   // slot sign
        uint32_t* cq = cw + q * 8;
        cq[0] = bc_u32(__floats2half2_rn(A, A));
        cq[1] = bc_u32(__floats2half2_rn(Bc, s1 * Bc));
        cq[2] = bc_u32(__floats2half2_rn(-C, -s1 * C));
        cq[3] = bc_u32(__floats2half2_rn(D, D));
        cq[4] = bc_u32(__floats2half2_rn(-D, -D));
        cq[5] = 0; cq[6] = 0; cq[7] = 0;
    }
    {
        // wtab[hl][k*2+slot] = signed fc_w sum at phys index sigma2(sigma1(amp))
        const int whl = t >> 4, wk = (t >> 1) & 7, wslot = t & 1;
        const int s = amp_index(wslot, wk, whl);
        int j = 0;
#pragma unroll
        for (int b = 0; b < 8; ++b)
            if ((s >> b) & 1) j ^= colmask2(b);
        float w = 0.f;
#pragma unroll
        for (int q = 0; q < 8; ++q)
            w += ((j >> (7 - q)) & 1) ? -fc_w[q] : fc_w[q];
        wtab[whl * 20 + wk * 2 + wslot] = w;
    }
    __syncthreads();

    // --- main path: 4 samples/wave, 16 lanes each, 16 amps/lane (8 re + 8 im f16x2) ---
    const int lane = t & 63;
    const int hl   = lane & 15;
    const int samp = (int)((blockIdx.x * blockDim.x + t) >> 6) * 4 + (lane >> 4);
    if (samp >= B) return;

    const float4 x0 = ((const float4*)(x + samp * NQ))[0];
    const float4 x1 = ((const float4*)(x + samp * NQ))[1];
    const float xq[8] = {x0.x, x0.y, x0.z, x0.w, x1.x, x1.y, x1.z, x1.w};

    // lane qubits q2..q5 <-> hl bits 3..0: selected column via pointer offset, chain
    float cr, ci;
    {
        const float* g = g0 + 2 * 8 + ((hl >> 3) & 1) * 4;
        float sn, cs; __sincosf(xq[2] * 0.5f, &sn, &cs);
        cr = cs * g[0] + sn * g[3];
        ci = cs * g[1] - sn * g[2];
    }
#pragma unroll
    for (int q = 3; q < 6; ++q) {
        const float* g = g0 + q * 8 + ((hl >> (5 - q)) & 1) * 4;
        float sn, cs; __sincosf(xq[q] * 0.5f, &sn, &cs);
        const float yr = cs * g[0] + sn * g[3];
        const float yi = cs * g[1] - sn * g[2];
        cmul(cr, ci, cr, ci, yr, yi);
    }

    // reg qubits q1(k2), q6(k1), q7(k0) and slot qubit q0: full columns
    float a1r, a1i, b1r, b1i, a6r, a6i, b6r, b6i, a7r, a7i, b7r, b7i, a0r, a0i, b0r, b0i;
    colq(g0 + 1 * 8, xq[1] * 0.5f, a1r, a1i, b1r, b1i);
    colq(g0 + 6 * 8, xq[6] * 0.5f, a6r, a6i, b6r, b6i);
    colq(g0 + 7 * 8, xq[7] * 0.5f, a7r, a7i, b7r, b7i);
    colq(g0 + 0 * 8, xq[0] * 0.5f, a0r, a0i, b0r, b0i);

    float u1r[2], u1i[2];
    cmul(u1r[0], u1i[0], cr, ci, a1r, a1i);
    cmul(u1r[1], u1i[1], cr, ci, b1r, b1i);
    float u2r[4], u2i[4];
    cmul(u2r[0], u2i[0], u1r[0], u1i[0], a6r, a6i);
    cmul(u2r[1], u2i[1], u1r[0], u1i[0], b6r, b6i);
    cmul(u2r[2], u2i[2], u1r[1], u1i[1], a6r, a6i);
    cmul(u2r[3], u2i[3], u1r[1], u1i[1], b6r, b6i);
    float u3r[8], u3i[8];
#pragma unroll
    for (int k = 0; k < 8; ++k) {
        const float vr = (k & 1) ? b7r : a7r;
        const float vi = (k & 1) ? b7i : a7i;
        cmul(u3r[k], u3i[k], u2r[k >> 1], u2i[k >> 1], vr, vi);
    }

    // slot stage (q0) in packed f16: re[k] = {amp(k,0).re, amp(k,1).re}, etc.
    const __half2 Vre  = __floats2half2_rn(a0r, b0r);
    const __half2 Vim  = __floats2half2_rn(a0i, b0i);
    const __half2 Vimn = bc_h2(bc_u32(Vim) ^ 0x80008000u);
    __half2 re[8], im[8];
#pragma unroll
    for (int k = 0; k < 8; ++k) {
        const __half2 Ur = __floats2half2_rn(u3r[k], u3r[k]);
        const __half2 Ui = __floats2half2_rn(u3i[k], u3i[k]);
        re[k] = __hfma2(Ui, Vimn, __hmul2(Ur, Vre));
        im[k] = __hfma2(Ui, Vre,  __hmul2(Ur, Vim));
    }

    // layer-2 Rot gates (CNOT layers folded away)
    gateQ<0>(re, im, hl, cw);
    gateQ<1>(re, im, hl, cw);
    gateQ<2>(re, im, hl, cw);
    gateQ<3>(re, im, hl, cw);
    gateQ<4>(re, im, hl, cw);
    gateQ<5>(re, im, hl, cw);
    gateQ<6>(re, im, hl, cw);
    gateQ<7>(re, im, hl, cw);

    // readout: f32 squares (keeps round-5 error profile), weighted sum, reduce over 16
    const float* wl = wtab + hl * 20;
    const float4 w0 = *(const float4*)(wl + 0);
    const float4 w1 = *(const float4*)(wl + 4);
    const float4 w2 = *(const float4*)(wl + 8);
    const float4 w3 = *(const float4*)(wl + 12);
    const float wv[16] = {w0.x, w0.y, w0.z, w0.w, w1.x, w1.y, w1.z, w1.w,
                          w2.x, w2.y, w2.z, w2.w, w3.x, w3.y, w3.z, w3.w};

    float acc = 0.f;
#pragma unroll
    for (int k = 0; k < 8; ++k) {
        const float rl_ = __low2float(re[k]),  rh_ = __high2float(re[k]);
        const float il_ = __low2float(im[k]),  ih_ = __high2float(im[k]);
        acc = fmaf(rl_ * rl_ + il_ * il_, wv[k * 2 + 0], acc);
        acc = fmaf(rh_ * rh_ + ih_ * ih_, wv[k * 2 + 1], acc);
    }
    acc += swzf<1>(acc);
    acc += swzf<2>(acc);
    acc += swzf<4>(acc);
    acc += swzf<8>(acc);

    if (hl == 0) {
        const float z = acc + fc_b[0];
        out[samp] = 1.0f / (1.0f + __expf(-z));
    }
}

extern "C" void kernel_launch(void* const* d_in, const int* in_sizes, int n_in,
                              void* d_out, int out_size, void* d_ws, size_t ws_size,
                              hipStream_t stream) {
    const float* x       = (const float*)d_in[0];
    const float* weights = (const float*)d_in[1];
    const float* fc_w    = (const float*)d_in[2];
    const float* fc_b    = (const float*)d_in[3];
    float* out = (float*)d_out;

    const int B = in_sizes[0] / NQ;        // 32768
    const int waves  = (B + 3) / 4;        // 4 samples per wave
    const int blocks = (waves + 3) / 4;    // 4 waves per 256-thread block

    vqe_fused<<<blocks, 256, 0, stream>>>(x, weights, fc_w, fc_b, out, B);
}

// Round 7
// 18.788 us; speedup vs baseline: 5.1638x; 1.1167x over previous
//
#include <hip/hip_runtime.h>
#include <hip/hip_fp16.h>
#include <math.h>

#define NQ 8

// ---------- compile-time GF(2) circuit algebra (validated: rounds 2-6) ----------
// wire w <-> amp-index bit (7-w). CNOT(c,t): bit_t ^= bit_c.
__host__ __device__ constexpr int cnot_step(int i, int c, int t) {
    return ((i >> (7 - c)) & 1) ? (i ^ (1 << (7 - t))) : i;
}
__host__ __device__ constexpr int sigma_fwd(int i, int r) {
    for (int q = 0; q < 8; ++q) i = cnot_step(i, q, (q + r) & 7);
    return i;
}
__host__ __device__ constexpr int sigma_inv(int i, int r) {
    for (int q = 7; q >= 0; --q) i = cnot_step(i, q, (q + r) & 7);
    return i;
}
__host__ __device__ constexpr int pairmask(int q) { return sigma_inv(1 << (7 - q), 1); }
__host__ __device__ constexpr int rolemask(int q) {
    int m = 0;
    for (int j = 0; j < 8; ++j)
        if ((sigma_fwd(1 << j, 1) >> (7 - q)) & 1) m |= 1 << j;
    return m;
}
__host__ __device__ constexpr int colmask2(int b) {
    return sigma_fwd(sigma_fwd(1 << b, 1), 2);
}

// ---------- amp-index bit assignment (4 samples/wave, 16 amps/lane, SoA f16x2) ----------
// amp s bits: b7=slot, b6=k2, b5=l3, b4=l2, b3=l1, b2=l0, b1=k1, b0=k0
__host__ __device__ constexpr int amp_index(int slot, int k, int hl) {
    return (slot << 7) | (((k >> 2) & 1) << 6) | (((hl >> 3) & 1) << 5)
         | (((hl >> 2) & 1) << 4) | (((hl >> 1) & 1) << 3) | ((hl & 1) << 2)
         | (((k >> 1) & 1) << 1) | (k & 1);
}
__host__ __device__ constexpr int mask_slot(int M) { return (M >> 7) & 1; }
__host__ __device__ constexpr int mask_k(int M) {
    return (((M >> 6) & 1) << 2) | (((M >> 1) & 1) << 1) | (M & 1);
}
__host__ __device__ constexpr int mask_l(int M) { return (M >> 2) & 15; }

typedef _Float16 h2v __attribute__((ext_vector_type(2)));

__device__ __forceinline__ __half2 bc_h2(uint32_t u) { return __builtin_bit_cast(__half2, u); }
__device__ __forceinline__ uint32_t bc_u32(__half2 h) { return __builtin_bit_cast(uint32_t, h); }
__device__ __forceinline__ h2v bc_hv(__half2 h) { return __builtin_bit_cast(h2v, h); }
__device__ __forceinline__ uint32_t rot16(uint32_t u) { return (u >> 16) | (u << 16); }

// lane' = lane ^ XM (XM<16 stays within each 16-lane sample group)
template<int XM>
__device__ __forceinline__ uint32_t swzu(uint32_t v) {
    return (uint32_t)__builtin_amdgcn_ds_swizzle((int)v, (XM << 10) | 0x1F);
}
template<int XM>
__device__ __forceinline__ float swzf(float v) {
    return __builtin_bit_cast(float, (uint32_t)__builtin_amdgcn_ds_swizzle(
        (int)__builtin_bit_cast(uint32_t, v), (XM << 10) | 0x1F));
}

__device__ __forceinline__ void cmul(float& zr, float& zi,
                                     float xr, float xi, float yr, float yi) {
    const float tr = xr * yr - xi * yi;
    const float ti = xr * yi + xi * yr;
    zr = tr; zi = ti;
}

// packed complex pair {slot0, slot1}
struct H2C { __half2 re, im; };
// z = x * y, y broadcast scalar complex given as (yre,yre),(yim,yim),(-yim,-yim)
__device__ __forceinline__ H2C h2c_mul(H2C x, __half2 yre, __half2 yim, __half2 yimn) {
    H2C z;
    z.re = __hfma2(x.im, yimn, __hmul2(x.re, yre));
    z.im = __hfma2(x.im, yre,  __hmul2(x.re, yim));
    return z;
}

// ---------- generalized layer-2 gate, SoA packed f16, 16 amps/lane ----------
template<int Q>
__device__ __forceinline__ void gateQ(__half2 re[8], __half2 im[8], int hl,
                                      const uint32_t* __restrict__ cw)
{
    constexpr int M  = pairmask(Q);
    constexpr int RM = rolemask(Q);
    constexpr int mk = mask_k(M);
    constexpr int ml = mask_l(M);
    constexpr int ms = mask_slot(M);
    constexpr int rk = mask_k(RM);
    constexpr int rl = mask_l(RM);

    const uint4    c4v = *(const uint4*)(cw + Q * 8); // {WA, WB0, WC0(-C), WD}
    const uint32_t WDn = cw[Q * 8 + 4];               // {-D,-D}

    const uint32_t pm = (uint32_t)(__popc(hl & rl) & 1) * 0x80008000u;
    const uint32_t Bp = c4v.y ^ pm, Bn = Bp ^ 0x80008000u;
    const uint32_t Cp = c4v.z ^ pm, Cn = Cp ^ 0x80008000u;
    const __half2  Aw = bc_h2(c4v.x);
    const __half2  Dw = bc_h2(c4v.w);
    const __half2  Dn = bc_h2(WDn);

    auto prep = [](uint32_t v) -> uint32_t {
        if constexpr (ms) v = rot16(v);
        if constexpr (ml) v = swzu<ml>(v);
        return v;
    };
    auto upd = [&](int k, uint32_t pr, uint32_t pi) {
        const bool par = (__popc(k & rk) & 1) != 0;   // compile-time after unroll
        const __half2 B1 = bc_h2(par ? Bn : Bp);
        const __half2 B2 = bc_h2(par ? Bp : Bn);
        const __half2 Cc = bc_h2(par ? Cn : Cp);
        __half2 nr = __hmul2(Aw, re[k]);
        nr = __hfma2(B1, im[k], nr);
        nr = __hfma2(Cc, bc_h2(pr), nr);
        nr = __hfma2(Dw, bc_h2(pi), nr);
        __half2 ni = __hmul2(Aw, im[k]);
        ni = __hfma2(B2, re[k], ni);
        ni = __hfma2(Cc, bc_h2(pi), ni);
        ni = __hfma2(Dn, bc_h2(pr), ni);
        re[k] = nr; im[k] = ni;
    };

    if constexpr (mk == 0) {
#pragma unroll
        for (int k = 0; k < 8; ++k) {
            const uint32_t pr = prep(bc_u32(re[k]));
            const uint32_t pi = prep(bc_u32(im[k]));
            upd(k, pr, pi);
        }
    } else {
        constexpr int msb = (mk & 4) ? 4 : ((mk & 2) ? 2 : 1);
#pragma unroll
        for (int k = 0; k < 8; ++k) {
            if ((k & msb) != 0) continue;            // compile-time (unrolled)
            const int k2 = k ^ mk;
            const uint32_t pr_k  = prep(bc_u32(re[k2]));
            const uint32_t pi_k  = prep(bc_u32(im[k2]));
            const uint32_t pr_k2 = prep(bc_u32(re[k]));
            const uint32_t pi_k2 = prep(bc_u32(im[k]));
            upd(k,  pr_k,  pi_k);
            upd(k2, pr_k2, pi_k2);
        }
    }
}

// ---------- single fused kernel: block = 16 samples, cooperative setup ----------
__global__ __launch_bounds__(256, 8) void vqe_fused(
    const float* __restrict__ x,       // (B,8)
    const float* __restrict__ weights, // (2,8,3)
    const float* __restrict__ fc_w,    // (8)
    const float* __restrict__ fc_b,    // (1)
    float* __restrict__ out, int B)
{
    __shared__ __align__(16) float    g0[64];        // layer-0 Rot entries (f32)
    __shared__ __align__(16) uint32_t cw[64];        // layer-1 coeff words, 8/gate
    __shared__ __align__(16) float    cols[16 * 36]; // [s][q][4]={ar,ai,br,bi}, stride 36
    __shared__ __align__(16) uint32_t wth2[16 * 12]; // [hl][k] f16x2 {w_slot0,w_slot1}, stride 12

    const int t = threadIdx.x;

    // --- phase A: shared trig (t<16) + packed weight table (t>=128) ---
    if (t < 8) {
        const float* w3 = weights + t * 3;
        float s, c;   __sincosf(w3[1] * 0.5f, &s, &c);
        float sa, ca; __sincosf(0.5f * (w3[0] + w3[2]), &sa, &ca);
        float sb, cb; __sincosf(0.5f * (w3[0] - w3[2]), &sb, &cb);
        float* g = g0 + t * 8;
        g[0] = c * ca;  g[1] = -c * sa;
        g[2] = -s * cb; g[3] = -s * sb;
        g[4] = s * cb;  g[5] = -s * sb;
        g[6] = c * ca;  g[7] = c * sa;
    } else if (t < 16) {
        const int q = t - 8;
        const float* w3 = weights + (NQ + q) * 3;
        float s, c;   __sincosf(w3[1] * 0.5f, &s, &c);
        float sa, ca; __sincosf(0.5f * (w3[0] + w3[2]), &sa, &ca);
        float sb, cb; __sincosf(0.5f * (w3[0] - w3[2]), &sb, &cb);
        const float A = c * ca, Bc = c * sa, C = s * cb, D = s * sb;
        const float s1 = (rolemask(q) & 0x80) ? -1.f : 1.f;   // slot sign
        uint32_t* cq = cw + q * 8;
        cq[0] = bc_u32(__floats2half2_rn(A, A));
        cq[1] = bc_u32(__floats2half2_rn(Bc, s1 * Bc));
        cq[2] = bc_u32(__floats2half2_rn(-C, -s1 * C));
        cq[3] = bc_u32(__floats2half2_rn(D, D));
        cq[4] = bc_u32(__floats2half2_rn(-D, -D));
        cq[5] = 0; cq[6] = 0; cq[7] = 0;
    } else if (t >= 128) {
        const int tt = t - 128;                // 0..127
        const int whl = tt >> 3, wk = tt & 7;
        float wsl[2];
#pragma unroll
        for (int slot = 0; slot < 2; ++slot) {
            const int s = amp_index(slot, wk, whl);
            int j = 0;
#pragma unroll
            for (int b = 0; b < 8; ++b)
                if ((s >> b) & 1) j ^= colmask2(b);
            float w = 0.f;
#pragma unroll
            for (int q = 0; q < 8; ++q)
                w += ((j >> (7 - q)) & 1) ? -fc_w[q] : fc_w[q];
            wsl[slot] = w;
        }
        wth2[whl * 12 + wk] = bc_u32(__floats2half2_rn(wsl[0], wsl[1]));
    }
    __syncthreads();

    // --- phase B: cooperative per-sample columns (1 sincos per thread) ---
    if (t < 128) {
        const int s = t >> 3, q = t & 7;
        const int sg = blockIdx.x * 16 + s;
        if (sg < B) {
            const float xv = x[sg * NQ + q];
            float sn, cs; __sincosf(xv * 0.5f, &sn, &cs);
            const float* g = g0 + q * 8;
            float* c = cols + s * 36 + q * 4;
            c[0] = cs * g[0] + sn * g[3];   // a_r
            c[1] = cs * g[1] - sn * g[2];   // a_i
            c[2] = cs * g[4] + sn * g[7];   // b_r
            c[3] = cs * g[5] - sn * g[6];   // b_i
        }
    }
    __syncthreads();

    // --- main: 4 samples/wave, 16 lanes each, 16 amps/lane (8 re + 8 im f16x2) ---
    const int lane = t & 63;
    const int hl   = lane & 15;
    const int sidx = ((t >> 6) << 2) | ((lane >> 4) & 3);
    const int samp = blockIdx.x * 16 + sidx;
    if (samp >= B) return;

    const float* cb = cols + sidx * 36;

    // lane qubits q2..q5 (hl bits 3..0): selected column halves, f32 chain
    const float2 e2 = *(const float2*)(cb + 2 * 4 + ((hl >> 3) & 1) * 2);
    const float2 e3 = *(const float2*)(cb + 3 * 4 + ((hl >> 2) & 1) * 2);
    const float2 e4 = *(const float2*)(cb + 4 * 4 + ((hl >> 1) & 1) * 2);
    const float2 e5 = *(const float2*)(cb + 5 * 4 + (hl & 1) * 2);
    float cr = e2.x, ci = e2.y;
    cmul(cr, ci, cr, ci, e3.x, e3.y);
    cmul(cr, ci, cr, ci, e4.x, e4.y);
    cmul(cr, ci, cr, ci, e5.x, e5.y);

    // full columns for slot qubit q0 and reg qubits q1(k2), q6(k1), q7(k0)
    const float4 c0 = *(const float4*)(cb + 0 * 4);
    const float4 c1 = *(const float4*)(cb + 1 * 4);
    const float4 c6 = *(const float4*)(cb + 6 * 4);
    const float4 c7 = *(const float4*)(cb + 7 * 4);

    // S over slot: {c*a0, c*b0} packed
    float w0r, w0i, w1r, w1i;
    cmul(w0r, w0i, cr, ci, c0.x, c0.y);
    cmul(w1r, w1i, cr, ci, c0.z, c0.w);
    H2C S{__floats2half2_rn(w0r, w1r), __floats2half2_rn(w0i, w1i)};

    // doubling tree in packed f16: k0 (q7), k1 (q6), k2 (q1)
    const __half2 y7ar = __floats2half2_rn(c7.x, c7.x), y7ai = __floats2half2_rn(c7.y, c7.y);
    const __half2 y7br = __floats2half2_rn(c7.z, c7.z), y7bi = __floats2half2_rn(c7.w, c7.w);
    const __half2 y7ain = bc_h2(bc_u32(y7ai) ^ 0x80008000u);
    const __half2 y7bin = bc_h2(bc_u32(y7bi) ^ 0x80008000u);
    H2C A0 = h2c_mul(S, y7ar, y7ai, y7ain);
    H2C A1 = h2c_mul(S, y7br, y7bi, y7bin);

    const __half2 y6ar = __floats2half2_rn(c6.x, c6.x), y6ai = __floats2half2_rn(c6.y, c6.y);
    const __half2 y6br = __floats2half2_rn(c6.z, c6.z), y6bi = __floats2half2_rn(c6.w, c6.w);
    const __half2 y6ain = bc_h2(bc_u32(y6ai) ^ 0x80008000u);
    const __half2 y6bin = bc_h2(bc_u32(y6bi) ^ 0x80008000u);
    H2C B0 = h2c_mul(A0, y6ar, y6ai, y6ain);
    H2C B1 = h2c_mul(A1, y6ar, y6ai, y6ain);
    H2C B2 = h2c_mul(A0, y6br, y6bi, y6bin);
    H2C B3 = h2c_mul(A1, y6br, y6bi, y6bin);

    const __half2 y1ar = __floats2half2_rn(c1.x, c1.x), y1ai = __floats2half2_rn(c1.y, c1.y);
    const __half2 y1br = __floats2half2_rn(c1.z, c1.z), y1bi = __floats2half2_rn(c1.w, c1.w);
    const __half2 y1ain = bc_h2(bc_u32(y1ai) ^ 0x80008000u);
    const __half2 y1bin = bc_h2(bc_u32(y1bi) ^ 0x80008000u);

    __half2 re[8], im[8];
    {
        H2C z;
        z = h2c_mul(B0, y1ar, y1ai, y1ain); re[0] = z.re; im[0] = z.im;
        z = h2c_mul(B1, y1ar, y1ai, y1ain); re[1] = z.re; im[1] = z.im;
        z = h2c_mul(B2, y1ar, y1ai, y1ain); re[2] = z.re; im[2] = z.im;
        z = h2c_mul(B3, y1ar, y1ai, y1ain); re[3] = z.re; im[3] = z.im;
        z = h2c_mul(B0, y1br, y1bi, y1bin); re[4] = z.re; im[4] = z.im;
        z = h2c_mul(B1, y1br, y1bi, y1bin); re[5] = z.re; im[5] = z.im;
        z = h2c_mul(B2, y1br, y1bi, y1bin); re[6] = z.re; im[6] = z.im;
        z = h2c_mul(B3, y1br, y1bi, y1bin); re[7] = z.re; im[7] = z.im;
    }

    // layer-2 Rot gates (CNOT layers folded away; algebra identical to round 6)
    gateQ<0>(re, im, hl, cw);
    gateQ<1>(re, im, hl, cw);
    gateQ<2>(re, im, hl, cw);
    gateQ<3>(re, im, hl, cw);
    gateQ<4>(re, im, hl, cw);
    gateQ<5>(re, im, hl, cw);
    gateQ<6>(re, im, hl, cw);
    gateQ<7>(re, im, hl, cw);

    // readout: acc += w*(re^2) + w*(im^2) via packed mul + v_dot2_f32_f16
    const uint32_t* wrow = wth2 + hl * 12;
    const uint4 wa = *(const uint4*)(wrow + 0);
    const uint4 wb = *(const uint4*)(wrow + 4);
    const uint32_t wk[8] = {wa.x, wa.y, wa.z, wa.w, wb.x, wb.y, wb.z, wb.w};

    float acc = 0.f;
#pragma unroll
    for (int k = 0; k < 8; ++k) {
        const __half2 W = bc_h2(wk[k]);
        const __half2 tr_ = __hmul2(re[k], W);
        const __half2 ti_ = __hmul2(im[k], W);
#if defined(__has_builtin) && __has_builtin(__builtin_amdgcn_fdot2)
        acc = __builtin_amdgcn_fdot2(bc_hv(tr_), bc_hv(re[k]), acc, false);
        acc = __builtin_amdgcn_fdot2(bc_hv(ti_), bc_hv(im[k]), acc, false);
#else
        acc += __low2float(tr_) * __low2float(re[k]) + __high2float(tr_) * __high2float(re[k]);
        acc += __low2float(ti_) * __low2float(im[k]) + __high2float(ti_) * __high2float(im[k]);
#endif
    }
    acc += swzf<1>(acc);
    acc += swzf<2>(acc);
    acc += swzf<4>(acc);
    acc += swzf<8>(acc);

    if (hl == 0) {
        const float z = acc + fc_b[0];
        out[samp] = 1.0f / (1.0f + __expf(-z));
    }
}

extern "C" void kernel_launch(void* const* d_in, const int* in_sizes, int n_in,
                              void* d_out, int out_size, void* d_ws, size_t ws_size,
                              hipStream_t stream) {
    const float* x       = (const float*)d_in[0];
    const float* weights = (const float*)d_in[1];
    const float* fc_w    = (const float*)d_in[2];
    const float* fc_b    = (const float*)d_in[3];
    float* out = (float*)d_out;

    const int B = in_sizes[0] / NQ;        // 32768
    const int blocks = (B + 15) / 16;      // 16 samples per 256-thread block

    vqe_fused<<<blocks, 256, 0, stream>>>(x, weights, fc_w, fc_b, out, B);
}

// Round 8
// 18.124 us; speedup vs baseline: 5.3530x; 1.0366x over previous
//
#include <hip/hip_runtime.h>
#include <hip/hip_fp16.h>
#include <math.h>

#define NQ 8

// ---------- compile-time GF(2) circuit algebra (validated: rounds 2-7, absmax=0 in f32) ----------
// wire w <-> amp-index bit (7-w). CNOT(c,t): bit_t ^= bit_c.
__host__ __device__ constexpr int cnot_step(int i, int c, int t) {
    return ((i >> (7 - c)) & 1) ? (i ^ (1 << (7 - t))) : i;
}
__host__ __device__ constexpr int sigma_fwd(int i, int r) {
    for (int q = 0; q < 8; ++q) i = cnot_step(i, q, (q + r) & 7);
    return i;
}
__host__ __device__ constexpr int sigma_inv(int i, int r) {
    for (int q = 7; q >= 0; --q) i = cnot_step(i, q, (q + r) & 7);
    return i;
}
__host__ __device__ constexpr int pairmask(int q) { return sigma_inv(1 << (7 - q), 1); }
__host__ __device__ constexpr int rolemask(int q) {
    int m = 0;
    for (int j = 0; j < 8; ++j)
        if ((sigma_fwd(1 << j, 1) >> (7 - q)) & 1) m |= 1 << j;
    return m;
}
__host__ __device__ constexpr int colmask2(int b) {
    return sigma_fwd(sigma_fwd(1 << b, 1), 2);
}

// ---------- amp-index bit assignment (8 samples/wave, 32 amps/lane, SoA f16x2) ----------
// b7=slot, b6=k3, b5=hl0, b4=hl1, b3=hl2, b2=k2, b1=k1, b0=k0
// wires: 0=slot, 1=k3, 2=hl0, 3=hl1, 4=hl2, 5=k2, 6=k1, 7=k0
// Gate-mask census: G0{b7,b6} local(rot16+k8), G1{b6,b5} k8+DPPxor1, G2{b5,b4} DPPxor3,
//                   G3{b4,b3} swz6, G4{b3,b2} swz4+k4, G5{b2,b1} k6, G6{b1,b0} k3,
//                   G7{b7,b6,b0} local(rot16+k9)
__host__ __device__ constexpr int amp_index(int slot, int k, int hl) {
    return (slot << 7) | (((k >> 3) & 1) << 6) | ((hl & 1) << 5) | (((hl >> 1) & 1) << 4)
         | (((hl >> 2) & 1) << 3) | (((k >> 2) & 1) << 2) | (((k >> 1) & 1) << 1) | (k & 1);
}
__host__ __device__ constexpr int mask_slot(int M) { return (M >> 7) & 1; }
__host__ __device__ constexpr int mask_k(int M) {
    return (((M >> 6) & 1) << 3) | (((M >> 2) & 1) << 2) | (((M >> 1) & 1) << 1) | (M & 1);
}
__host__ __device__ constexpr int mask_l(int M) {
    return ((M >> 5) & 1) | (((M >> 4) & 1) << 1) | (((M >> 3) & 1) << 2);
}

typedef _Float16 h2v __attribute__((ext_vector_type(2)));

__device__ __forceinline__ __half2 bc_h2(uint32_t u) { return __builtin_bit_cast(__half2, u); }
__device__ __forceinline__ uint32_t bc_u32(__half2 h) { return __builtin_bit_cast(uint32_t, h); }
__device__ __forceinline__ h2v bc_hv(__half2 h) { return __builtin_bit_cast(h2v, h); }
__device__ __forceinline__ uint32_t rot16(uint32_t u) { return (u >> 16) | (u << 16); }

// lane' = lane ^ XM via BitMode ds_swizzle (stays within 8-lane sample group for XM<8)
template<int XM>
__device__ __forceinline__ uint32_t swzu(uint32_t v) {
    return (uint32_t)__builtin_amdgcn_ds_swizzle((int)v, (XM << 10) | 0x1F);
}
// lane' = lane ^ {1,3} via quad-perm DPP (VALU, no LDS pipe)
// ctrl: xor1 = quad_perm(1,0,3,2) = 0xB1 ; xor3 = quad_perm(3,2,1,0) = 0x1B
template<int CTRL>
__device__ __forceinline__ uint32_t dppx(uint32_t v) {
    return (uint32_t)__builtin_amdgcn_update_dpp(0, (int)v, CTRL, 0xF, 0xF, true);
}
// reduction add with fused DPP permute: xor1=0xB1, xor2=0x4E, lane^7=row_half_mirror=0x141
template<int CTRL>
__device__ __forceinline__ float dppaddf(float v) {
    const uint32_t p = (uint32_t)__builtin_amdgcn_update_dpp(
        0, (int)__builtin_bit_cast(uint32_t, v), CTRL, 0xF, 0xF, true);
    return v + __builtin_bit_cast(float, p);
}

__device__ __forceinline__ void cmul(float& zr, float& zi,
                                     float xr, float xi, float yr, float yi) {
    const float tr = xr * yr - xi * yi;
    const float ti = xr * yi + xi * yr;
    zr = tr; zi = ti;
}

// packed complex pair {slot0, slot1} and broadcast complex coefficient
struct H2C { __half2 re, im; };
struct YB  { __half2 re, im, imn; };
__device__ __forceinline__ YB mkyb(float r, float i) {
    YB y;
    y.re  = __floats2half2_rn(r, r);
    y.im  = __floats2half2_rn(i, i);
    y.imn = bc_h2(bc_u32(y.im) ^ 0x80008000u);
    return y;
}
__device__ __forceinline__ H2C h2c_mul(H2C x, YB y) {
    H2C z;
    z.re = __hfma2(x.im, y.imn, __hmul2(x.re, y.re));
    z.im = __hfma2(x.im, y.re,  __hmul2(x.re, y.im));
    return z;
}

// ---------- generalized layer-2 gate, SoA packed f16, 32 amps/lane ----------
// role0: new = m00*z + m01*p ; role1: new = m10*p + m11*z ; with Rot structure:
// nre = A*zre + rB*zim - rC*pre + D*pim ; nim = A*zim - rB*zre - rC*pim - D*pre
template<int Q>
__device__ __forceinline__ void gateQ(__half2 re[16], __half2 im[16], int hl,
                                      const uint32_t* __restrict__ cw)
{
    constexpr int M  = pairmask(Q);
    constexpr int RM = rolemask(Q);
    constexpr int mk = mask_k(M);
    constexpr int ml = mask_l(M);
    constexpr int ms = mask_slot(M);
    constexpr int rk = mask_k(RM);
    constexpr int rl = mask_l(RM);

    const uint4    c4v = *(const uint4*)(cw + Q * 8); // {WA, WB0, WC0(-C), WD}
    const uint32_t WDn = cw[Q * 8 + 4];               // {-D,-D}

    const uint32_t pm = (uint32_t)(__popc(hl & rl) & 1) * 0x80008000u;
    const uint32_t Bp = c4v.y ^ pm, Bn = Bp ^ 0x80008000u;
    const uint32_t Cp = c4v.z ^ pm, Cn = Cp ^ 0x80008000u;
    const __half2  Aw = bc_h2(c4v.x);
    const __half2  Dw = bc_h2(c4v.w);
    const __half2  Dn = bc_h2(WDn);

    auto prep = [](uint32_t v) -> uint32_t {
        if constexpr (ms) v = rot16(v);
        if constexpr (ml == 1) v = dppx<0xB1>(v);
        else if constexpr (ml == 3) v = dppx<0x1B>(v);
        else if constexpr (ml != 0) v = swzu<ml>(v);
        return v;
    };
    auto upd = [&](int k, uint32_t pr, uint32_t pi) {
        const bool par = (__popc(k & rk) & 1) != 0;   // compile-time after unroll
        const __half2 B1 = bc_h2(par ? Bn : Bp);
        const __half2 B2 = bc_h2(par ? Bp : Bn);
        const __half2 Cc = bc_h2(par ? Cn : Cp);
        __half2 nr = __hmul2(Aw, re[k]);
        nr = __hfma2(B1, im[k], nr);
        nr = __hfma2(Cc, bc_h2(pr), nr);
        nr = __hfma2(Dw, bc_h2(pi), nr);
        __half2 ni = __hmul2(Aw, im[k]);
        ni = __hfma2(B2, re[k], ni);
        ni = __hfma2(Cc, bc_h2(pi), ni);
        ni = __hfma2(Dn, bc_h2(pr), ni);
        re[k] = nr; im[k] = ni;
    };

    if constexpr (mk == 0) {
#pragma unroll
        for (int k = 0; k < 16; ++k) {
            const uint32_t pr = prep(bc_u32(re[k]));
            const uint32_t pi = prep(bc_u32(im[k]));
            upd(k, pr, pi);
        }
    } else {
        constexpr int msb = (mk & 8) ? 8 : ((mk & 4) ? 4 : ((mk & 2) ? 2 : 1));
#pragma unroll
        for (int k = 0; k < 16; ++k) {
            if ((k & msb) != 0) continue;            // compile-time (unrolled)
            const int k2 = k ^ mk;
            const uint32_t pr_k  = prep(bc_u32(re[k2]));
            const uint32_t pi_k  = prep(bc_u32(im[k2]));
            const uint32_t pr_k2 = prep(bc_u32(re[k]));
            const uint32_t pi_k2 = prep(bc_u32(im[k]));
            upd(k,  pr_k,  pi_k);
            upd(k2, pr_k2, pi_k2);
        }
    }
}

// ---------- single fused kernel: block = 32 samples, cooperative setup ----------
__global__ __launch_bounds__(256, 4) void vqe_fused(
    const float* __restrict__ x,       // (B,8)
    const float* __restrict__ weights, // (2,8,3)
    const float* __restrict__ fc_w,    // (8)
    const float* __restrict__ fc_b,    // (1)
    float* __restrict__ out, int B)
{
    __shared__ __align__(16) float    g0[64];        // layer-0 Rot entries (f32)
    __shared__ __align__(16) uint32_t cw[64];        // layer-1 coeff words, 8/gate
    __shared__ __align__(16) float    cols[32 * 36]; // [s][q][4]={ar,ai,br,bi}, stride 36
    __shared__ __align__(16) uint32_t wth2[8 * 20];  // [hl][k] f16x2 {w_s0,w_s1}, stride 20

    const int t = threadIdx.x;

    // --- phase A: shared trig (t<16) + packed weight table (t>=128) ---
    if (t < 8) {
        const float* w3 = weights + t * 3;
        float s, c;   __sincosf(w3[1] * 0.5f, &s, &c);
        float sa, ca; __sincosf(0.5f * (w3[0] + w3[2]), &sa, &ca);
        float sb, cb; __sincosf(0.5f * (w3[0] - w3[2]), &sb, &cb);
        float* g = g0 + t * 8;
        g[0] = c * ca;  g[1] = -c * sa;
        g[2] = -s * cb; g[3] = -s * sb;
        g[4] = s * cb;  g[5] = -s * sb;
        g[6] = c * ca;  g[7] = c * sa;
    } else if (t < 16) {
        const int q = t - 8;
        const float* w3 = weights + (NQ + q) * 3;
        float s, c;   __sincosf(w3[1] * 0.5f, &s, &c);
        float sa, ca; __sincosf(0.5f * (w3[0] + w3[2]), &sa, &ca);
        float sb, cb; __sincosf(0.5f * (w3[0] - w3[2]), &sb, &cb);
        const float A = c * ca, Bc = c * sa, C = s * cb, D = s * sb;
        const float s1 = (rolemask(q) & 0x80) ? -1.f : 1.f;   // slot-bit role sign
        uint32_t* cq = cw + q * 8;
        cq[0] = bc_u32(__floats2half2_rn(A, A));
        cq[1] = bc_u32(__floats2half2_rn(Bc, s1 * Bc));
        cq[2] = bc_u32(__floats2half2_rn(-C, -s1 * C));
        cq[3] = bc_u32(__floats2half2_rn(D, D));
        cq[4] = bc_u32(__floats2half2_rn(-D, -D));
        cq[5] = 0; cq[6] = 0; cq[7] = 0;
    } else if (t >= 128) {
        const int tt = t - 128;                // 0..127
        const int whl = tt >> 4, wk = tt & 15;
        float wsl[2];
#pragma unroll
        for (int slot = 0; slot < 2; ++slot) {
            const int s = amp_index(slot, wk, whl);
            int j = 0;
#pragma unroll
            for (int b = 0; b < 8; ++b)
                if ((s >> b) & 1) j ^= colmask2(b);
            float w = 0.f;
#pragma unroll
            for (int q = 0; q < 8; ++q)
                w += ((j >> (7 - q)) & 1) ? -fc_w[q] : fc_w[q];
            wsl[slot] = w;
        }
        wth2[whl * 20 + wk] = bc_u32(__floats2half2_rn(wsl[0], wsl[1]));
    }
    __syncthreads();

    // --- phase B: cooperative per-sample columns (1 sincos per thread, all 256) ---
    {
        const int s = t >> 3, q = t & 7;
        const int sg = blockIdx.x * 32 + s;
        if (sg < B) {
            const float xv = x[sg * NQ + q];   // addr = blockIdx*256 + t : coalesced
            float sn, cs; __sincosf(xv * 0.5f, &sn, &cs);
            const float* g = g0 + q * 8;
            float* c = cols + s * 36 + q * 4;
            c[0] = cs * g[0] + sn * g[3];   // a_r
            c[1] = cs * g[1] - sn * g[2];   // a_i
            c[2] = cs * g[4] + sn * g[7];   // b_r
            c[3] = cs * g[5] - sn * g[6];   // b_i
        }
    }
    __syncthreads();

    // --- main: 8 samples/wave, 8 lanes each, 32 amps/lane (16 re + 16 im f16x2) ---
    const int lane = t & 63;
    const int hl   = lane & 7;
    const int sidx = ((t >> 6) << 3) | ((lane >> 3) & 7);   // 0..31
    const int samp = blockIdx.x * 32 + sidx;
    if (samp >= B) return;

    const float* cb = cols + sidx * 36;

    // lane wires 2,3,4 <- hl bits 0,1,2: selected column halves, f32 chain
    const float2 e2 = *(const float2*)(cb + 2 * 4 + (hl & 1) * 2);
    const float2 e3 = *(const float2*)(cb + 3 * 4 + ((hl >> 1) & 1) * 2);
    const float2 e4 = *(const float2*)(cb + 4 * 4 + ((hl >> 2) & 1) * 2);
    float cr = e2.x, ci = e2.y;
    cmul(cr, ci, cr, ci, e3.x, e3.y);
    cmul(cr, ci, cr, ci, e4.x, e4.y);

    // full columns: wire0 (slot), wire1 (k3), wire5 (k2), wire6 (k1), wire7 (k0)
    const float4 c0 = *(const float4*)(cb + 0 * 4);
    const float4 c1 = *(const float4*)(cb + 1 * 4);
    const float4 c5 = *(const float4*)(cb + 5 * 4);
    const float4 c6 = *(const float4*)(cb + 6 * 4);
    const float4 c7 = *(const float4*)(cb + 7 * 4);

    // slot stage: S = {c*a0, c*b0}
    float w0r, w0i, w1r, w1i;
    cmul(w0r, w0i, cr, ci, c0.x, c0.y);
    cmul(w1r, w1i, cr, ci, c0.z, c0.w);
    H2C S{__floats2half2_rn(w0r, w1r), __floats2half2_rn(w0i, w1i)};

    // doubling tree over reg qubits k3(wire1), k2(wire5), k1(wire6), k0(wire7)
    const YB y1a = mkyb(c1.x, c1.y), y1b = mkyb(c1.z, c1.w);
    const YB y5a = mkyb(c5.x, c5.y), y5b = mkyb(c5.z, c5.w);
    const YB y6a = mkyb(c6.x, c6.y), y6b = mkyb(c6.z, c6.w);
    const YB y7a = mkyb(c7.x, c7.y), y7b = mkyb(c7.z, c7.w);

    const H2C A0 = h2c_mul(S, y1a);
    const H2C A1 = h2c_mul(S, y1b);
    H2C Bv[4];
    Bv[0] = h2c_mul(A0, y5a); Bv[1] = h2c_mul(A0, y5b);
    Bv[2] = h2c_mul(A1, y5a); Bv[3] = h2c_mul(A1, y5b);
    H2C Cv[8];
#pragma unroll
    for (int j = 0; j < 4; ++j) {
        Cv[j * 2 + 0] = h2c_mul(Bv[j], y6a);
        Cv[j * 2 + 1] = h2c_mul(Bv[j], y6b);
    }
    __half2 re[16], im[16];
#pragma unroll
    for (int j = 0; j < 8; ++j) {
        const H2C z0 = h2c_mul(Cv[j], y7a);
        const H2C z1 = h2c_mul(Cv[j], y7b);
        re[j * 2 + 0] = z0.re; im[j * 2 + 0] = z0.im;
        re[j * 2 + 1] = z1.re; im[j * 2 + 1] = z1.im;
    }

    // layer-2 Rot gates (CNOT layers folded away; algebra validated rounds 2-7)
    gateQ<0>(re, im, hl, cw);
    gateQ<1>(re, im, hl, cw);
    gateQ<2>(re, im, hl, cw);
    gateQ<3>(re, im, hl, cw);
    gateQ<4>(re, im, hl, cw);
    gateQ<5>(re, im, hl, cw);
    gateQ<6>(re, im, hl, cw);
    gateQ<7>(re, im, hl, cw);

    // readout: acc += w*(re^2 + im^2) via packed mul + v_dot2_f32_f16
    const uint32_t* wrow = wth2 + hl * 20;
    const uint4 wa = *(const uint4*)(wrow + 0);
    const uint4 wb = *(const uint4*)(wrow + 4);
    const uint4 wc = *(const uint4*)(wrow + 8);
    const uint4 wd = *(const uint4*)(wrow + 12);
    const uint32_t wkw[16] = {wa.x, wa.y, wa.z, wa.w, wb.x, wb.y, wb.z, wb.w,
                              wc.x, wc.y, wc.z, wc.w, wd.x, wd.y, wd.z, wd.w};

    float acc = 0.f;
#pragma unroll
    for (int k = 0; k < 16; ++k) {
        const __half2 W = bc_h2(wkw[k]);
        const __half2 tr_ = __hmul2(re[k], W);
        const __half2 ti_ = __hmul2(im[k], W);
#if defined(__has_builtin) && __has_builtin(__builtin_amdgcn_fdot2)
        acc = __builtin_amdgcn_fdot2(bc_hv(tr_), bc_hv(re[k]), acc, false);
        acc = __builtin_amdgcn_fdot2(bc_hv(ti_), bc_hv(im[k]), acc, false);
#else
        acc += __low2float(tr_) * __low2float(re[k]) + __high2float(tr_) * __high2float(re[k]);
        acc += __low2float(ti_) * __low2float(im[k]) + __high2float(ti_) * __high2float(im[k]);
#endif
    }
    // 8-lane reduce: DPP xor1, xor2, lane^7 (row_half_mirror)
    acc = dppaddf<0xB1>(acc);
    acc = dppaddf<0x4E>(acc);
    acc = dppaddf<0x141>(acc);

    if (hl == 0) {
        const float z = acc + fc_b[0];
        out[samp] = 1.0f / (1.0f + __expf(-z));
    }
}

extern "C" void kernel_launch(void* const* d_in, const int* in_sizes, int n_in,
                              void* d_out, int out_size, void* d_ws, size_t ws_size,
                              hipStream_t stream) {
    const float* x       = (const float*)d_in[0];
    const float* weights = (const float*)d_in[1];
    const float* fc_w    = (const float*)d_in[2];
    const float* fc_b    = (const float*)d_in[3];
    float* out = (float*)d_out;
    (void)d_ws; (void)ws_size;

    const int B = in_sizes[0] / NQ;        // 32768
    const int blocks = (B + 31) / 32;      // 32 samples per 256-thread block

    vqe_fused<<<blocks, 256, 0, stream>>>(x, weights, fc_w, fc_b, out, B);
}